// Round 14
// baseline (73.040 us; speedup 1.0000x reference)
//
#include <hip/hip_runtime.h>
#include <hip/hip_bf16.h>

using f32x4 = __attribute__((ext_vector_type(4))) float;
using s16x8 = __attribute__((ext_vector_type(8))) short;
using u32x4 = __attribute__((ext_vector_type(4))) unsigned;

// Problem dims (fixed by reference setup_inputs)
constexpr int Bn = 4, Cc = 32, Hh = 256, Ww = 256;
constexpr int H2 = 128, W2 = 128;
constexpr int NF = 128;                 // KAN feature dim (= W2)
constexpr long NROWS = (long)Bn * Cc * 4 * H2;  // 65536 KAN rows
constexpr int KTOT = 1152;              // 128 features x 9 (silu + 8 bases)
constexpr int KCH = 288;                // K-chunk: 32 features x 9

// ---- bf16 round-to-nearest-even ----
__device__ __forceinline__ short f2bf(float f) {
    union { float f; unsigned u; } v; v.f = f;
    unsigned r = v.u + 0x7fffu + ((v.u >> 16) & 1u);
    return (short)(r >> 16);
}

// hardware bf16 pair pack (v_cvt_pk_bf16_f32)
__device__ __forceinline__ unsigned pk_bf16(float a, float b) {
    union { __hip_bfloat162 h; unsigned u; } c;
    c.h.x = __float2bfloat16(a);
    c.h.y = __float2bfloat16(b);
    return c.u;
}

// Place [wD,wC,wB,wA] (bf16-packed u64) at slot (ci-3) of an 8-slot 128-bit
// window; slots outside [0,7] dropped. ci guaranteed in [0,10] by caller.
__device__ __forceinline__ void window128(float wD, float wC, float wB, float wA,
                                          int ci, unsigned W[4]) {
    unsigned long long P = ((unsigned long long)pk_bf16(wB, wA) << 32)
                         | (unsigned long long)pk_bf16(wD, wC);
    int sh = ci * 16 - 48;
    unsigned long long sl = P << (sh & 63);
    unsigned long long sr = P >> ((-sh) & 63);
    unsigned long long lo = (sh < 0) ? sr : ((sh < 64) ? sl : 0ull);
    int shh = sh - 64;
    unsigned long long sl2 = P << (shh & 63);
    unsigned long long sr2 = P >> ((-shh) & 63);
    unsigned long long hi = (shh >= 0) ? sl2 : (((-shh) < 64) ? sr2 : 0ull);
    W[0] = (unsigned)lo; W[1] = (unsigned)(lo >> 32);
    W[2] = (unsigned)hi; W[3] = (unsigned)(hi >> 32);
}

// ---- KW: bf16 weight matrix in MFMA-FRAGMENT order ----
// Bg[tile][lane][q], tile = (ni*4 + jg)*9 + ks  (ni:8, jg:4, ks:9 -> 288 tiles)
// lane holds col o = ni*16 + (lane&15), k = jg*288 + ks*32 + (lane>>4)*8 + q.
__global__ __launch_bounds__(256) void k_wbuild(const float* __restrict__ base_w,
                                                const float* __restrict__ spline_w,
                                                const float* __restrict__ scaler,
                                                short* __restrict__ Bg) {
    int idx = blockIdx.x * 256 + threadIdx.x;   // 147456 total
    int tile = idx >> 9;                        // /512 shorts per tile
    int r = idx & 511;
    int lane = r >> 3, q = r & 7;
    int ni = tile / 36; int rem = tile - ni * 36;
    int jg = rem / 9;   int ks = rem - jg * 9;
    int o = ni * 16 + (lane & 15);
    int kk = ks * 32 + (lane >> 4) * 8 + q;     // 0..287 within K-chunk
    int g = kk >> 5, jl = kk & 31;
    int j = jg * 32 + jl;
    float v = (g == 0) ? base_w[o * NF + j]
                       : spline_w[(long)(o * NF + j) * 8 + (g - 1)] * scaler[o * NF + j];
    Bg[idx] = f2bf(v);
}

// ---- K3: LDS-shared-B register-fragment KAN ----
// block = 256 thr = 4 waves = (plane, 32-i-row band); wave = one kcomp.
// Per jg: stage 72KB B-chunk to LDS (reg-staged, latency hidden under
// expansion), then 9 ks-steps of conflict-free ds_read_b128 + MFMA.
// jg walk order staggered per block to spread L2 traffic.
__global__ __launch_bounds__(256, 2) void k_fused(const float* __restrict__ x,
                                                  float* __restrict__ z,
                                                  const short* __restrict__ Bg) {
    __shared__ __align__(16) short Bsh[72 * 512];   // 72 KB -> 2 blocks/CU
    const int t = threadIdx.x;
    const int lane = t & 63;
    const int w = t >> 6;                       // wave id = kcomp 0..3
    const int blk = blockIdx.x;                 // plane*4 + band
    const int plane = blk >> 2;
    const int band = blk & 3;
    const int i0 = band << 5;                   // 32 i-rows per block
    const int jg0 = blk & 3;                    // stagger start jg
    const int il = lane & 15;                   // i_local within 16-tile
    const int fg = lane >> 4;                   // k-subslice 0..3

    // Haar signs for this wave's kcomp
    const float sB = (w & 2) ? -1.f : 1.f;
    const float sC = (w & 1) ? -1.f : 1.f;
    const float sD = sB * sC;

    const float* xbase = x + (long)plane * Hh * Ww;
    const float* xr0a = xbase + (long)(2 * (i0 + il)) * Ww;        // mi=0
    const float* xr1a = xr0a + Ww;
    const float* xr0b = xbase + (long)(2 * (i0 + il + 16)) * Ww;   // mi=1
    const float* xr1b = xr0b + Ww;

    f32x4 acc[2][8];
#pragma unroll
    for (int mi = 0; mi < 2; ++mi)
#pragma unroll
        for (int ni = 0; ni < 8; ++ni)
            acc[mi][ni] = (f32x4){0.f, 0.f, 0.f, 0.f};

    for (int j = 0; j < 4; ++j) {
        const int jg = (jg0 + j) & 3;
        const int cb = jg * 64 + fg * 16;       // x column base (16 floats)

        // --- issue B stage loads (wave stages tile q = s*4+w per step s) ---
        s16x8 stg[18];
#pragma unroll
        for (int s = 0; s < 18; ++s) {
            int q = s * 4 + w;                  // LDS tile 0..71 (ni*9+ks)
            int ni = q / 9, ks = q - ni * 9;
            stg[s] = *(const s16x8*)&Bg[(long)(((ni * 4 + jg) * 9 + ks) << 9) + lane * 8];
        }

        u32x4 afr[2][9];                        // A-fragments [mi][g]
        // --- expansion (register-only; covers stage-load latency) ---
#pragma unroll
        for (int mi = 0; mi < 2; ++mi) {
            const float* r0 = mi ? xr0b : xr0a;
            const float* r1 = mi ? xr1b : xr1a;
#pragma unroll
            for (int p = 0; p < 4; ++p) {       // feature pairs
                f32x4 va = *(const f32x4*)(r0 + cb + 4 * p);
                f32x4 vb = *(const f32x4*)(r1 + cb + 4 * p);
                float vv[2];
                vv[0] = 0.5f * (va[0] + sB * va[1] + sC * vb[0] + sD * vb[1]);
                vv[1] = 0.5f * (va[2] + sB * va[3] + sC * vb[2] + sD * vb[3]);
                float sl2[2]; unsigned Wf[2][4];
#pragma unroll
                for (int e = 0; e < 2; ++e) {
                    float v = vv[e];
                    float ex = __builtin_amdgcn_exp2f(-1.442695040888963f * v);
                    sl2[e] = v * __builtin_amdgcn_rcpf(1.0f + ex);      // silu
                    float xs = __builtin_fmaf(v, 2.5f, 5.5f);           // (v+2.2)*2.5
                    xs = fminf(fmaxf(xs, 0.0f), 10.999f);               // med3 clamp
                    float cf = floorf(xs);
                    float u = xs - cf;
                    int ci = (int)cf;                                   // 0..10
                    float u2 = u * u, u3 = u2 * u;
                    float wA = u3 * (1.f / 6.f);
                    float wB = (1.f + 3.f * u + 3.f * u2 - 3.f * u3) * (1.f / 6.f);
                    float wC = (4.f - 6.f * u2 + 3.f * u3) * (1.f / 6.f);
                    float um = 1.f - u;
                    float wD = um * um * um * (1.f / 6.f);
                    window128(wD, wC, wB, wA, ci, Wf[e]);
                }
                afr[mi][0][p] = pk_bf16(sl2[0], sl2[1]);
#pragma unroll
                for (int g = 1; g <= 8; ++g) {
                    int wq = (g - 1) >> 1;
                    unsigned sel = ((g - 1) & 1) ? 0x07060302u : 0x05040100u;
                    afr[mi][g][p] = __builtin_amdgcn_perm(Wf[1][wq], Wf[0][wq], sel);
                }
            }
        }

        // --- commit staged B to LDS (data arrived during expansion) ---
#pragma unroll
        for (int s = 0; s < 18; ++s) {
            int q = s * 4 + w;
            *(s16x8*)&Bsh[(q << 9) + lane * 8] = stg[s];
        }
        __syncthreads();                        // B(jg) visible to all waves

        // --- MFMA sweep from LDS: 9 ks x 2 mi x 8 ni ---
#pragma unroll
        for (int ks = 0; ks < 9; ++ks) {
            s16x8 bfr[8];
#pragma unroll
            for (int ni = 0; ni < 8; ++ni)
                bfr[ni] = *(const s16x8*)&Bsh[((ni * 9 + ks) << 9) + lane * 8];
#pragma unroll
            for (int mi = 0; mi < 2; ++mi) {
                s16x8 a = __builtin_bit_cast(s16x8, afr[mi][ks]);
#pragma unroll
                for (int ni = 0; ni < 8; ++ni)
                    acc[mi][ni] = __builtin_amdgcn_mfma_f32_16x16x32_bf16(
                        a, bfr[ni], acc[mi][ni], 0, 0, 0);
            }
        }
        __syncthreads();                        // all reads done before re-stage
    }

    // epilogue: kcomp = w; z row = i0 + mi*16 + fg*4+rr, col = ni*16 + il
#pragma unroll
    for (int mi = 0; mi < 2; ++mi) {
        long nb = ((long)(plane * 4 + w) * H2 + i0 + mi * 16) * NF;
#pragma unroll
        for (int rr = 0; rr < 4; ++rr) {
            long rowb = nb + (long)(fg * 4 + rr) * NF + il;
#pragma unroll
            for (int ni = 0; ni < 8; ++ni)
                z[rowb + ni * 16] = acc[mi][ni][rr];
        }
    }
}

// ---- K4: depthwise 5x5 conv + bias + inverse Haar -> out (final) ----
__global__ __launch_bounds__(256) void k_invconv(const float* __restrict__ x,
                                                 const float* __restrict__ cw,
                                                 const float* __restrict__ cb,
                                                 const float* __restrict__ z,
                                                 float* __restrict__ out) {
    __shared__ float sx[68][70];                // 19040 B, padded stride
    const int t = threadIdx.x;
    const int blk = blockIdx.x;
    const int tile = blk & 15;                  // 4x4 tiles of 64x64
    const int plane = blk >> 4;                 // b*32+c
    const int ty = tile >> 2, tx = tile & 3;
    const int c = plane & 31;
    const int Y0 = ty * 64, X0 = tx * 64;
    const float* xp = x + (long)plane * Hh * Ww;

    for (int idx = t; idx < 68 * 68; idx += 256) {
        int rr = idx / 68, cc2 = idx - rr * 68;
        int yy = Y0 - 2 + rr, xxp = X0 - 2 + cc2;
        float v = 0.f;
        if (yy >= 0 && yy < Hh && xxp >= 0 && xxp < Ww) v = xp[(long)yy * Ww + xxp];
        sx[rr][cc2] = v;
    }
    float w[25];
#pragma unroll
    for (int q = 0; q < 25; ++q) w[q] = cw[c * 25 + q];
    const float bias = cb[c];
    __syncthreads();

    const long zbase = (long)plane * 4 * H2 * W2;
    const long zplane = (long)H2 * W2;
#pragma unroll
    for (int p = 0; p < 4; ++p) {
        int q = t + p * 256;                    // quad id in 32x32
        int qy = q >> 5, qx = q & 31;
        int i = (Y0 >> 1) + qy, j = (X0 >> 1) + qx;
        long zi = zbase + (long)i * W2 + j;
        float z0 = z[zi];
        float z1 = z[zi + zplane];
        float z2 = z[zi + 2 * zplane];
        float z3 = z[zi + 3 * zplane];
        float y00 = 0.5f * (z0 + z1 + z2 + z3);
        float y01 = 0.5f * (z0 + z1 - z2 - z3);
        float y10 = 0.5f * (z0 - z1 + z2 - z3);
        float y11 = 0.5f * (z0 - z1 - z2 + z3);

        float vals[6][6];
#pragma unroll
        for (int rr = 0; rr < 6; ++rr)
#pragma unroll
            for (int c2 = 0; c2 < 3; ++c2) {
                float2 vv = *(const float2*)&sx[2 * qy + rr][2 * qx + 2 * c2];
                vals[rr][2 * c2] = vv.x; vals[rr][2 * c2 + 1] = vv.y;
            }
        float a00 = bias, a01 = bias, a10 = bias, a11 = bias;
#pragma unroll
        for (int ky = 0; ky < 5; ++ky)
#pragma unroll
            for (int kx = 0; kx < 5; ++kx) {
                float wvv = w[ky * 5 + kx];
                a00 += wvv * vals[ky][kx];
                a01 += wvv * vals[ky][kx + 1];
                a10 += wvv * vals[ky + 1][kx];
                a11 += wvv * vals[ky + 1][kx + 1];
            }
        float* op = out + (long)plane * Hh * Ww + (long)(Y0 + 2 * qy) * Ww + X0 + 2 * qx;
        *(float2*)op = make_float2(a00 + y00, a01 + y01);
        *(float2*)(op + Ww) = make_float2(a10 + y10, a11 + y11);
    }
}

extern "C" void kernel_launch(void* const* d_in, const int* in_sizes, int n_in,
                              void* d_out, int out_size, void* d_ws, size_t ws_size,
                              hipStream_t stream) {
    const float* x        = (const float*)d_in[0];
    const float* conv_w   = (const float*)d_in[1];
    const float* conv_b   = (const float*)d_in[2];
    const float* base_w   = (const float*)d_in[3];
    const float* spline_w = (const float*)d_in[4];
    const float* scaler   = (const float*)d_in[5];
    float* out = (float*)d_out;
    float* z   = (float*)d_ws;              // 65536 x 128 fp32 = 32 MiB
    short* Bg  = (short*)d_out;             // 288 KB staged in d_out (overwritten by k_invconv)

    // 1) fragment-order bf16 weights into d_out scratch
    k_wbuild<<<(NF * KTOT) / 256, 256, 0, stream>>>(base_w, spline_w, scaler, Bg);
    // 2) LDS-shared-B KAN -> z (512 blocks x 256 thr, wave = kcomp)
    k_fused<<<512, 256, 0, stream>>>(x, z, Bg);
    // 3) conv + inverse Haar -> out (fully overwrites d_out incl. Bg region)
    k_invconv<<<Bn * Cc * 16, 256, 0, stream>>>(x, conv_w, conv_b, z, out);
}

// Round 15
// 67.494 us; speedup vs baseline: 1.0822x; 1.0822x over previous
//
#include <hip/hip_runtime.h>
#include <hip/hip_bf16.h>

using f32x4 = __attribute__((ext_vector_type(4))) float;
using s16x8 = __attribute__((ext_vector_type(8))) short;
using u32x4 = __attribute__((ext_vector_type(4))) unsigned;

// Problem dims (fixed by reference setup_inputs)
constexpr int Bn = 4, Cc = 32, Hh = 256, Ww = 256;
constexpr int H2 = 128, W2 = 128;
constexpr int NF = 128;                 // KAN feature dim (= W2)
constexpr long NROWS = (long)Bn * Cc * 4 * H2;  // 65536 KAN rows
constexpr int KTOT = 1152;              // 128 features x 9 (silu + 8 bases)
constexpr int KCH = 288;                // K-chunk: 32 features x 9

// ---- bf16 round-to-nearest-even ----
__device__ __forceinline__ short f2bf(float f) {
    union { float f; unsigned u; } v; v.f = f;
    unsigned r = v.u + 0x7fffu + ((v.u >> 16) & 1u);
    return (short)(r >> 16);
}

// hardware bf16 pair pack (v_cvt_pk_bf16_f32)
__device__ __forceinline__ unsigned pk_bf16(float a, float b) {
    union { __hip_bfloat162 h; unsigned u; } c;
    c.h.x = __float2bfloat16(a);
    c.h.y = __float2bfloat16(b);
    return c.u;
}

// direct HBM/L2 -> LDS, 16B per lane, no VGPR round-trip
__device__ __forceinline__ void gload_lds16(const void* g, void* l) {
    __builtin_amdgcn_global_load_lds(
        (const __attribute__((address_space(1))) unsigned*)g,
        (__attribute__((address_space(3))) unsigned*)l, 16, 0, 0);
}

// Place [wD,wC,wB,wA] (bf16-packed u64) at slot (ci-3) of an 8-slot 128-bit
// window; slots outside [0,7] dropped. ci guaranteed in [0,10] by caller.
__device__ __forceinline__ void window128(float wD, float wC, float wB, float wA,
                                          int ci, unsigned W[4]) {
    unsigned long long P = ((unsigned long long)pk_bf16(wB, wA) << 32)
                         | (unsigned long long)pk_bf16(wD, wC);
    int sh = ci * 16 - 48;
    unsigned long long sl = P << (sh & 63);
    unsigned long long sr = P >> ((-sh) & 63);
    unsigned long long lo = (sh < 0) ? sr : ((sh < 64) ? sl : 0ull);
    int shh = sh - 64;
    unsigned long long sl2 = P << (shh & 63);
    unsigned long long sr2 = P >> ((-shh) & 63);
    unsigned long long hi = (shh >= 0) ? sl2 : (((-shh) < 64) ? sr2 : 0ull);
    W[0] = (unsigned)lo; W[1] = (unsigned)(lo >> 32);
    W[2] = (unsigned)hi; W[3] = (unsigned)(hi >> 32);
}

// ---- KW: bf16 weight matrix in MFMA-FRAGMENT order ----
// Bg[tile][lane][q], tile = (ni*4 + jg)*9 + ks  (ni:8, jg:4, ks:9 -> 288 tiles)
// lane holds col o = ni*16 + (lane&15), k = jg*288 + ks*32 + (lane>>4)*8 + q.
__global__ __launch_bounds__(256) void k_wbuild(const float* __restrict__ base_w,
                                                const float* __restrict__ spline_w,
                                                const float* __restrict__ scaler,
                                                short* __restrict__ Bg) {
    int idx = blockIdx.x * 256 + threadIdx.x;   // 147456 total
    int tile = idx >> 9;                        // /512 shorts per tile
    int r = idx & 511;
    int lane = r >> 3, q = r & 7;
    int ni = tile / 36; int rem = tile - ni * 36;
    int jg = rem / 9;   int ks = rem - jg * 9;
    int o = ni * 16 + (lane & 15);
    int kk = ks * 32 + (lane >> 4) * 8 + q;     // 0..287 within K-chunk
    int g = kk >> 5, jl = kk & 31;
    int j = jg * 32 + jl;
    float v = (g == 0) ? base_w[o * NF + j]
                       : spline_w[(long)(o * NF + j) * 8 + (g - 1)] * scaler[o * NF + j];
    Bg[idx] = f2bf(v);
}

// ---- K3: LDS-shared-B KAN, B staged via global_load_lds (zero reg cost) ----
// block = 256 thr = 4 waves = (plane, 32-i-row band); wave = one kcomp.
// Per jg: issue 18 gload_lds (1KB tiles) -> expansion covers latency ->
// barrier (vmcnt drained, loads already complete) -> MFMA from LDS.
__global__ __launch_bounds__(256, 2) void k_fused(const float* __restrict__ x,
                                                  float* __restrict__ z,
                                                  const short* __restrict__ Bg) {
    __shared__ __align__(16) short Bsh[72 * 512];   // 72 KB -> 2 blocks/CU
    const int t = threadIdx.x;
    const int lane = t & 63;
    const int w = t >> 6;                       // wave id = kcomp 0..3
    const int blk = blockIdx.x;                 // plane*4 + band
    const int plane = blk >> 2;
    const int band = blk & 3;
    const int i0 = band << 5;                   // 32 i-rows per block
    const int jg0 = blk & 3;                    // stagger start jg
    const int il = lane & 15;                   // i_local within 16-tile
    const int fg = lane >> 4;                   // k-subslice 0..3

    // Haar signs for this wave's kcomp
    const float sB = (w & 2) ? -1.f : 1.f;
    const float sC = (w & 1) ? -1.f : 1.f;
    const float sD = sB * sC;

    const float* xbase = x + (long)plane * Hh * Ww;
    const float* xr0a = xbase + (long)(2 * (i0 + il)) * Ww;        // mi=0
    const float* xr1a = xr0a + Ww;
    const float* xr0b = xbase + (long)(2 * (i0 + il + 16)) * Ww;   // mi=1
    const float* xr1b = xr0b + Ww;

    f32x4 acc[2][8];
#pragma unroll
    for (int mi = 0; mi < 2; ++mi)
#pragma unroll
        for (int ni = 0; ni < 8; ++ni)
            acc[mi][ni] = (f32x4){0.f, 0.f, 0.f, 0.f};

    for (int j = 0; j < 4; ++j) {
        const int jg = (jg0 + j) & 3;
        const int cb = jg * 64 + fg * 16;       // x column base (16 floats)

        // --- issue B stage via global_load_lds (wave w -> tiles s*4+w) ---
#pragma unroll
        for (int s = 0; s < 18; ++s) {
            int q = s * 4 + w;                  // LDS tile 0..71 (ni*9+ks)
            int ni = q / 9, ks = q - ni * 9;
            gload_lds16(&Bg[(long)(((ni * 4 + jg) * 9 + ks) << 9) + lane * 8],
                        &Bsh[q << 9]);
        }

        u32x4 afr[2][9];                        // A-fragments [mi][g]
        // --- expansion (register-only; covers stage-load latency) ---
#pragma unroll
        for (int mi = 0; mi < 2; ++mi) {
            const float* r0 = mi ? xr0b : xr0a;
            const float* r1 = mi ? xr1b : xr1a;
#pragma unroll
            for (int p = 0; p < 4; ++p) {       // feature pairs
                f32x4 va = *(const f32x4*)(r0 + cb + 4 * p);
                f32x4 vb = *(const f32x4*)(r1 + cb + 4 * p);
                float vv[2];
                vv[0] = 0.5f * (va[0] + sB * va[1] + sC * vb[0] + sD * vb[1]);
                vv[1] = 0.5f * (va[2] + sB * va[3] + sC * vb[2] + sD * vb[3]);
                float sl2[2]; unsigned Wf[2][4];
#pragma unroll
                for (int e = 0; e < 2; ++e) {
                    float v = vv[e];
                    float ex = __builtin_amdgcn_exp2f(-1.442695040888963f * v);
                    sl2[e] = v * __builtin_amdgcn_rcpf(1.0f + ex);      // silu
                    float xs = __builtin_fmaf(v, 2.5f, 5.5f);           // (v+2.2)*2.5
                    xs = fminf(fmaxf(xs, 0.0f), 10.999f);               // med3 clamp
                    float cf = floorf(xs);
                    float u = xs - cf;
                    int ci = (int)cf;                                   // 0..10
                    float u2 = u * u, u3 = u2 * u;
                    float wA = u3 * (1.f / 6.f);
                    float wB = (1.f + 3.f * u + 3.f * u2 - 3.f * u3) * (1.f / 6.f);
                    float wC = (4.f - 6.f * u2 + 3.f * u3) * (1.f / 6.f);
                    float um = 1.f - u;
                    float wD = um * um * um * (1.f / 6.f);
                    window128(wD, wC, wB, wA, ci, Wf[e]);
                }
                afr[mi][0][p] = pk_bf16(sl2[0], sl2[1]);
#pragma unroll
                for (int g = 1; g <= 8; ++g) {
                    int wq = (g - 1) >> 1;
                    unsigned sel = ((g - 1) & 1) ? 0x07060302u : 0x05040100u;
                    afr[mi][g][p] = __builtin_amdgcn_perm(Wf[1][wq], Wf[0][wq], sel);
                }
            }
        }

        __syncthreads();                        // vmcnt drained: B(jg) in LDS

        // --- MFMA sweep from LDS: 9 ks x 2 mi x 8 ni ---
#pragma unroll
        for (int ks = 0; ks < 9; ++ks) {
            s16x8 bfr[8];
#pragma unroll
            for (int ni = 0; ni < 8; ++ni)
                bfr[ni] = *(const s16x8*)&Bsh[((ni * 9 + ks) << 9) + lane * 8];
#pragma unroll
            for (int mi = 0; mi < 2; ++mi) {
                s16x8 a = __builtin_bit_cast(s16x8, afr[mi][ks]);
#pragma unroll
                for (int ni = 0; ni < 8; ++ni)
                    acc[mi][ni] = __builtin_amdgcn_mfma_f32_16x16x32_bf16(
                        a, bfr[ni], acc[mi][ni], 0, 0, 0);
            }
        }
        __syncthreads();                        // all reads done before re-stage
    }

    // epilogue: kcomp = w; z row = i0 + mi*16 + fg*4+rr, col = ni*16 + il
#pragma unroll
    for (int mi = 0; mi < 2; ++mi) {
        long nb = ((long)(plane * 4 + w) * H2 + i0 + mi * 16) * NF;
#pragma unroll
        for (int rr = 0; rr < 4; ++rr) {
            long rowb = nb + (long)(fg * 4 + rr) * NF + il;
#pragma unroll
            for (int ni = 0; ni < 8; ++ni)
                z[rowb + ni * 16] = acc[mi][ni][rr];
        }
    }
}

// ---- K4: depthwise 5x5 conv + bias + inverse Haar -> out (final) ----
__global__ __launch_bounds__(256) void k_invconv(const float* __restrict__ x,
                                                 const float* __restrict__ cw,
                                                 const float* __restrict__ cb,
                                                 const float* __restrict__ z,
                                                 float* __restrict__ out) {
    __shared__ float sx[68][70];                // 19040 B, padded stride
    const int t = threadIdx.x;
    const int blk = blockIdx.x;
    const int tile = blk & 15;                  // 4x4 tiles of 64x64
    const int plane = blk >> 4;                 // b*32+c
    const int ty = tile >> 2, tx = tile & 3;
    const int c = plane & 31;
    const int Y0 = ty * 64, X0 = tx * 64;
    const float* xp = x + (long)plane * Hh * Ww;

    for (int idx = t; idx < 68 * 68; idx += 256) {
        int rr = idx / 68, cc2 = idx - rr * 68;
        int yy = Y0 - 2 + rr, xxp = X0 - 2 + cc2;
        float v = 0.f;
        if (yy >= 0 && yy < Hh && xxp >= 0 && xxp < Ww) v = xp[(long)yy * Ww + xxp];
        sx[rr][cc2] = v;
    }
    float w[25];
#pragma unroll
    for (int q = 0; q < 25; ++q) w[q] = cw[c * 25 + q];
    const float bias = cb[c];
    __syncthreads();

    const long zbase = (long)plane * 4 * H2 * W2;
    const long zplane = (long)H2 * W2;
#pragma unroll
    for (int p = 0; p < 4; ++p) {
        int q = t + p * 256;                    // quad id in 32x32
        int qy = q >> 5, qx = q & 31;
        int i = (Y0 >> 1) + qy, j = (X0 >> 1) + qx;
        long zi = zbase + (long)i * W2 + j;
        float z0 = z[zi];
        float z1 = z[zi + zplane];
        float z2 = z[zi + 2 * zplane];
        float z3 = z[zi + 3 * zplane];
        float y00 = 0.5f * (z0 + z1 + z2 + z3);
        float y01 = 0.5f * (z0 + z1 - z2 - z3);
        float y10 = 0.5f * (z0 - z1 + z2 - z3);
        float y11 = 0.5f * (z0 - z1 - z2 + z3);

        float vals[6][6];
#pragma unroll
        for (int rr = 0; rr < 6; ++rr)
#pragma unroll
            for (int c2 = 0; c2 < 3; ++c2) {
                float2 vv = *(const float2*)&sx[2 * qy + rr][2 * qx + 2 * c2];
                vals[rr][2 * c2] = vv.x; vals[rr][2 * c2 + 1] = vv.y;
            }
        float a00 = bias, a01 = bias, a10 = bias, a11 = bias;
#pragma unroll
        for (int ky = 0; ky < 5; ++ky)
#pragma unroll
            for (int kx = 0; kx < 5; ++kx) {
                float wvv = w[ky * 5 + kx];
                a00 += wvv * vals[ky][kx];
                a01 += wvv * vals[ky][kx + 1];
                a10 += wvv * vals[ky + 1][kx];
                a11 += wvv * vals[ky + 1][kx + 1];
            }
        float* op = out + (long)plane * Hh * Ww + (long)(Y0 + 2 * qy) * Ww + X0 + 2 * qx;
        *(float2*)op = make_float2(a00 + y00, a01 + y01);
        *(float2*)(op + Ww) = make_float2(a10 + y10, a11 + y11);
    }
}

extern "C" void kernel_launch(void* const* d_in, const int* in_sizes, int n_in,
                              void* d_out, int out_size, void* d_ws, size_t ws_size,
                              hipStream_t stream) {
    const float* x        = (const float*)d_in[0];
    const float* conv_w   = (const float*)d_in[1];
    const float* conv_b   = (const float*)d_in[2];
    const float* base_w   = (const float*)d_in[3];
    const float* spline_w = (const float*)d_in[4];
    const float* scaler   = (const float*)d_in[5];
    float* out = (float*)d_out;
    float* z   = (float*)d_ws;              // 65536 x 128 fp32 = 32 MiB
    short* Bg  = (short*)d_out;             // 288 KB staged in d_out (overwritten by k_invconv)

    // 1) fragment-order bf16 weights into d_out scratch
    k_wbuild<<<(NF * KTOT) / 256, 256, 0, stream>>>(base_w, spline_w, scaler, Bg);
    // 2) LDS-shared-B KAN via global_load_lds -> z (512 blocks x 256 thr)
    k_fused<<<512, 256, 0, stream>>>(x, z, Bg);
    // 3) conv + inverse Haar -> out (fully overwrites d_out incl. Bg region)
    k_invconv<<<Bn * Cc * 16, 256, 0, stream>>>(x, conv_w, conv_b, z, out);
}

// Round 16
// 56.389 us; speedup vs baseline: 1.2953x; 1.1969x over previous
//
#include <hip/hip_runtime.h>
#include <hip/hip_bf16.h>

using f32x4 = __attribute__((ext_vector_type(4))) float;
using s16x8 = __attribute__((ext_vector_type(8))) short;
using u32x4 = __attribute__((ext_vector_type(4))) unsigned;

// Problem dims (fixed by reference setup_inputs)
constexpr int Bn = 4, Cc = 32, Hh = 256, Ww = 256;
constexpr int H2 = 128, W2 = 128;
constexpr int NF = 128;                 // KAN feature dim (= W2)
constexpr int KTOT = 1152;              // 128 features x 9 (silu + 8 bases)

// ---- bf16 round-to-nearest-even ----
__device__ __forceinline__ short f2bf(float f) {
    union { float f; unsigned u; } v; v.f = f;
    unsigned r = v.u + 0x7fffu + ((v.u >> 16) & 1u);
    return (short)(r >> 16);
}

// hardware bf16 pair pack (v_cvt_pk_bf16_f32)
__device__ __forceinline__ unsigned pk_bf16(float a, float b) {
    union { __hip_bfloat162 h; unsigned u; } c;
    c.h.x = __float2bfloat16(a);
    c.h.y = __float2bfloat16(b);
    return c.u;
}

// direct HBM/L2 -> LDS, 16B per lane, no VGPR round-trip
__device__ __forceinline__ void gload_lds16(const void* g, void* l) {
    __builtin_amdgcn_global_load_lds(
        (const __attribute__((address_space(1))) unsigned*)g,
        (__attribute__((address_space(3))) unsigned*)l, 16, 0, 0);
}

// Place [wD,wC,wB,wA] (bf16-packed u64) at slot (ci-3) of an 8-slot 128-bit
// window; slots outside [0,7] dropped. ci guaranteed in [0,10] by caller.
__device__ __forceinline__ void window128(float wD, float wC, float wB, float wA,
                                          int ci, unsigned W[4]) {
    unsigned long long P = ((unsigned long long)pk_bf16(wB, wA) << 32)
                         | (unsigned long long)pk_bf16(wD, wC);
    int sh = ci * 16 - 48;
    unsigned long long sl = P << (sh & 63);
    unsigned long long sr = P >> ((-sh) & 63);
    unsigned long long lo = (sh < 0) ? sr : ((sh < 64) ? sl : 0ull);
    int shh = sh - 64;
    unsigned long long sl2 = P << (shh & 63);
    unsigned long long sr2 = P >> ((-shh) & 63);
    unsigned long long hi = (shh >= 0) ? sl2 : (((-shh) < 64) ? sr2 : 0ull);
    W[0] = (unsigned)lo; W[1] = (unsigned)(lo >> 32);
    W[2] = (unsigned)hi; W[3] = (unsigned)(hi >> 32);
}

// ---- KW: bf16 weight matrix in MFMA-FRAGMENT order (into d_ws) ----
// Bg[tile][lane][q], tile = (ni*4 + jg)*9 + ks  (ni:8, jg:4, ks:9 -> 288 tiles)
__global__ __launch_bounds__(256) void k_wbuild(const float* __restrict__ base_w,
                                                const float* __restrict__ spline_w,
                                                const float* __restrict__ scaler,
                                                short* __restrict__ Bg) {
    int idx = blockIdx.x * 256 + threadIdx.x;   // 147456 total
    int tile = idx >> 9;
    int r = idx & 511;
    int lane = r >> 3, q = r & 7;
    int ni = tile / 36; int rem = tile - ni * 36;
    int jg = rem / 9;   int ks = rem - jg * 9;
    int o = ni * 16 + (lane & 15);
    int kk = ks * 32 + (lane >> 4) * 8 + q;
    int g = kk >> 5, jl = kk & 31;
    int j = jg * 32 + jl;
    float v = (g == 0) ? base_w[o * NF + j]
                       : spline_w[(long)(o * NF + j) * 8 + (g - 1)] * scaler[o * NF + j];
    Bg[idx] = f2bf(v);
}

// load 6 floats at x-cols [2j-2, 2j+3] with edge guards (j in 0..127)
__device__ __forceinline__ void ldrow6(const float* xrp, int j, bool rok, float o[6]) {
    float2 lo = (rok && j >= 1)   ? *(const float2*)(xrp + 2 * j - 2) : make_float2(0.f, 0.f);
    float2 mi = rok               ? *(const float2*)(xrp + 2 * j)     : make_float2(0.f, 0.f);
    float2 hi = (rok && j <= 126) ? *(const float2*)(xrp + 2 * j + 2) : make_float2(0.f, 0.f);
    o[0] = lo.x; o[1] = lo.y; o[2] = mi.x; o[3] = mi.y; o[4] = hi.x; o[5] = hi.y;
}

// ---- MEGA kernel: Haar + expand + MFMA KAN + invHaar + conv + skip -> out --
// block = 256 thr = 4 waves = (plane, 32-i-row band); wave = one kcomp.
// After GEMM, Bsh is reused as the z-exchange tile and the block finishes
// the whole pipeline, writing final output (no z round-trip, no 2nd kernel).
__global__ __launch_bounds__(256, 2) void k_fused(const float* __restrict__ x,
                                                  const float* __restrict__ cw,
                                                  const float* __restrict__ cb,
                                                  float* __restrict__ out,
                                                  const short* __restrict__ Bg) {
    __shared__ __align__(16) short Bsh[72 * 512];   // 72 KB (B stage / z tile)
    const int t = threadIdx.x;
    const int lane = t & 63;
    const int w = t >> 6;                       // wave id = kcomp 0..3
    const int blk = blockIdx.x;                 // plane*4 + band
    const int plane = blk >> 2;
    const int band = blk & 3;
    const int i0 = band << 5;                   // 32 i-rows per block
    const int jg0 = blk & 3;                    // stagger start jg
    const int il = lane & 15;                   // i_local within 16-tile
    const int fg = lane >> 4;                   // k-subslice 0..3

    // Haar signs for this wave's kcomp
    const float sB = (w & 2) ? -1.f : 1.f;
    const float sC = (w & 1) ? -1.f : 1.f;
    const float sD = sB * sC;

    const float* xbase = x + (long)plane * Hh * Ww;
    const float* xr0a = xbase + (long)(2 * (i0 + il)) * Ww;        // mi=0
    const float* xr1a = xr0a + Ww;
    const float* xr0b = xbase + (long)(2 * (i0 + il + 16)) * Ww;   // mi=1
    const float* xr1b = xr0b + Ww;

    f32x4 acc[2][8];
#pragma unroll
    for (int mi = 0; mi < 2; ++mi)
#pragma unroll
        for (int ni = 0; ni < 8; ++ni)
            acc[mi][ni] = (f32x4){0.f, 0.f, 0.f, 0.f};

    for (int j = 0; j < 4; ++j) {
        const int jg = (jg0 + j) & 3;
        const int cb2 = jg * 64 + fg * 16;      // x column base (16 floats)

        // --- issue B stage via global_load_lds (wave w -> tiles s*4+w) ---
#pragma unroll
        for (int s = 0; s < 18; ++s) {
            int q = s * 4 + w;                  // LDS tile 0..71 (ni*9+ks)
            int ni = q / 9, ks = q - ni * 9;
            gload_lds16(&Bg[(long)(((ni * 4 + jg) * 9 + ks) << 9) + lane * 8],
                        &Bsh[q << 9]);
        }

        u32x4 afr[2][9];                        // A-fragments [mi][g]
        // --- expansion (register-only; covers stage-load latency) ---
#pragma unroll
        for (int mi = 0; mi < 2; ++mi) {
            const float* r0 = mi ? xr0b : xr0a;
            const float* r1 = mi ? xr1b : xr1a;
#pragma unroll
            for (int p = 0; p < 4; ++p) {       // feature pairs
                f32x4 va = *(const f32x4*)(r0 + cb2 + 4 * p);
                f32x4 vb = *(const f32x4*)(r1 + cb2 + 4 * p);
                float vv[2];
                vv[0] = 0.5f * (va[0] + sB * va[1] + sC * vb[0] + sD * vb[1]);
                vv[1] = 0.5f * (va[2] + sB * va[3] + sC * vb[2] + sD * vb[3]);
                float sl2[2]; unsigned Wf[2][4];
#pragma unroll
                for (int e = 0; e < 2; ++e) {
                    float v = vv[e];
                    float ex = __builtin_amdgcn_exp2f(-1.442695040888963f * v);
                    sl2[e] = v * __builtin_amdgcn_rcpf(1.0f + ex);      // silu
                    float xs = __builtin_fmaf(v, 2.5f, 5.5f);           // (v+2.2)*2.5
                    xs = fminf(fmaxf(xs, 0.0f), 10.999f);               // med3 clamp
                    float cf = floorf(xs);
                    float u = xs - cf;
                    int ci = (int)cf;                                   // 0..10
                    float u2 = u * u, u3 = u2 * u;
                    float wA = u3 * (1.f / 6.f);
                    float wB = (1.f + 3.f * u + 3.f * u2 - 3.f * u3) * (1.f / 6.f);
                    float wC = (4.f - 6.f * u2 + 3.f * u3) * (1.f / 6.f);
                    float um = 1.f - u;
                    float wD = um * um * um * (1.f / 6.f);
                    window128(wD, wC, wB, wA, ci, Wf[e]);
                }
                afr[mi][0][p] = pk_bf16(sl2[0], sl2[1]);
#pragma unroll
                for (int g = 1; g <= 8; ++g) {
                    int wq = (g - 1) >> 1;
                    unsigned sel = ((g - 1) & 1) ? 0x07060302u : 0x05040100u;
                    afr[mi][g][p] = __builtin_amdgcn_perm(Wf[1][wq], Wf[0][wq], sel);
                }
            }
        }

        __syncthreads();                        // vmcnt drained: B(jg) in LDS

        // --- MFMA sweep from LDS: 9 ks x 2 mi x 8 ni ---
#pragma unroll
        for (int ks = 0; ks < 9; ++ks) {
            s16x8 bfr[8];
#pragma unroll
            for (int ni = 0; ni < 8; ++ni)
                bfr[ni] = *(const s16x8*)&Bsh[((ni * 9 + ks) << 9) + lane * 8];
#pragma unroll
            for (int mi = 0; mi < 2; ++mi) {
                s16x8 a = __builtin_bit_cast(s16x8, afr[mi][ks]);
#pragma unroll
                for (int ni = 0; ni < 8; ++ni)
                    acc[mi][ni] = __builtin_amdgcn_mfma_f32_16x16x32_bf16(
                        a, bfr[ni], acc[mi][ni], 0, 0, 0);
            }
        }
        __syncthreads();                        // all reads done before re-stage
    }

    // ---- z exchange through LDS (Bsh reused): zsh[kcomp*32+row][132] ----
    constexpr int ZP = 132;                     // padded stride -> 2-way banks
    float* zsh = (float*)Bsh;                   // 4*32*132*4B = 67.6 KB <= 72 KB
#pragma unroll
    for (int mi = 0; mi < 2; ++mi)
#pragma unroll
        for (int rr = 0; rr < 4; ++rr)
#pragma unroll
            for (int ni = 0; ni < 8; ++ni)
                zsh[(w * 32 + mi * 16 + fg * 4 + rr) * ZP + ni * 16 + il]
                    = acc[mi][ni][rr];
    __syncthreads();

    // ---- conv(5x5) + bias + inverse Haar + write final out ----
    const int c = plane & 31;
    float cwr[25];
#pragma unroll
    for (int q = 0; q < 25; ++q) cwr[q] = cw[c * 25 + q];
    const float bias = cb[c];
    float* outp = out + (long)plane * Hh * Ww;
    const int qyg = t >> 6;                     // quad-row group (reuse w)

#pragma unroll
    for (int qxh = 0; qxh < 2; ++qxh) {
        const int jq = qxh * 64 + lane;         // quad col 0..127
        float xv[6][6];
#pragma unroll
        for (int a = 0; a < 8; ++a) {
            const int ql = qyg * 8 + a;         // local quad row 0..31
            const int orow = 2 * (i0 + ql);     // global out row (even)
            if (a == 0) {
#pragma unroll
                for (int r6 = 0; r6 < 6; ++r6) {
                    int xr = orow - 2 + r6;
                    ldrow6(xbase + (long)xr * Ww, jq, xr >= 0 && xr < Hh, xv[r6]);
                }
            } else {                            // roll window down by 2 rows
#pragma unroll
                for (int r6 = 0; r6 < 4; ++r6)
#pragma unroll
                    for (int c6 = 0; c6 < 6; ++c6) xv[r6][c6] = xv[r6 + 2][c6];
#pragma unroll
                for (int r6 = 4; r6 < 6; ++r6) {
                    int xr = orow - 2 + r6;
                    ldrow6(xbase + (long)xr * Ww, jq, xr >= 0 && xr < Hh, xv[r6]);
                }
            }
            // inverse Haar from LDS
            float z0 = zsh[(ql) * ZP + jq];
            float z1 = zsh[(32 + ql) * ZP + jq];
            float z2 = zsh[(64 + ql) * ZP + jq];
            float z3 = zsh[(96 + ql) * ZP + jq];
            float y00 = 0.5f * (z0 + z1 + z2 + z3);
            float y01 = 0.5f * (z0 + z1 - z2 - z3);
            float y10 = 0.5f * (z0 - z1 + z2 - z3);
            float y11 = 0.5f * (z0 - z1 - z2 + z3);
            // 2x2 conv outputs
            float s00 = bias, s01 = bias, s10 = bias, s11 = bias;
#pragma unroll
            for (int ky = 0; ky < 5; ++ky)
#pragma unroll
                for (int kx = 0; kx < 5; ++kx) {
                    float wv = cwr[ky * 5 + kx];
                    s00 += wv * xv[ky][kx];
                    s01 += wv * xv[ky][kx + 1];
                    s10 += wv * xv[ky + 1][kx];
                    s11 += wv * xv[ky + 1][kx + 1];
                }
            float* op = outp + (long)orow * Ww + 2 * jq;
            *(float2*)op        = make_float2(s00 + y00, s01 + y01);
            *(float2*)(op + Ww) = make_float2(s10 + y10, s11 + y11);
        }
    }
}

extern "C" void kernel_launch(void* const* d_in, const int* in_sizes, int n_in,
                              void* d_out, int out_size, void* d_ws, size_t ws_size,
                              hipStream_t stream) {
    const float* x        = (const float*)d_in[0];
    const float* conv_w   = (const float*)d_in[1];
    const float* conv_b   = (const float*)d_in[2];
    const float* base_w   = (const float*)d_in[3];
    const float* spline_w = (const float*)d_in[4];
    const float* scaler   = (const float*)d_in[5];
    float* out = (float*)d_out;
    short* Bg  = (short*)d_ws;              // 288 KB fragment-order weights in ws

    // 1) fragment-order bf16 weights into ws
    k_wbuild<<<(NF * KTOT) / 256, 256, 0, stream>>>(base_w, spline_w, scaler, Bg);
    // 2) fully-fused pipeline -> final out (512 blocks x 256 thr)
    k_fused<<<512, 256, 0, stream>>>(x, conv_w, conv_b, out, Bg);
}